// Round 20
// baseline (2585.438 us; speedup 1.0000x reference)
//
#include <hip/hip_runtime.h>
#include <hip/hip_bf16.h>
#include <math.h>

// Problem constants (from reference)
#define BB 64
#define TT 2048
#define VV 4096
#define EE 128
#define H2 128
#define SS 8
#define CC 2

typedef _Float16 h2f __attribute__((ext_vector_type(2)));

// v_rcp_f32 instead of precise IEEE divide (~15 instr) — round-19 verified
// win (-10% lstm_rec), ~1 ulp, well within 4.88e-4 tolerance.
__device__ __forceinline__ float fast_rcp(float x) {
#if __has_builtin(__builtin_amdgcn_rcpf)
    return __builtin_amdgcn_rcpf(x);
#else
    return 1.f / x;
#endif
}

__device__ __forceinline__ float sigf(float x) {
    return fast_rcp(1.f + __expf(-x));
}
__device__ __forceinline__ float tanh_fast(float x) {
    return fmaf(-2.f, fast_rcp(__expf(2.f * x) + 1.f), 1.f);
}

__device__ __forceinline__ float dot2acc(h2f w, h2f h, float acc) {
#if __has_builtin(__builtin_amdgcn_fdot2)
    return __builtin_amdgcn_fdot2(w, h, acc, false);
#else
    return fmaf((float)w.x, (float)h.x, fmaf((float)w.y, (float)h.y, acc));
#endif
}

// lane^1 swap as pure-VALU DPP (quad_perm [1,0,3,2] = ctrl 0xB1).
__device__ __forceinline__ float xor1_swap(float x) {
#if __has_builtin(__builtin_amdgcn_update_dpp)
    return __builtin_bit_cast(float,
        __builtin_amdgcn_update_dpp(0, __builtin_bit_cast(int, x),
                                    0xB1, 0xF, 0xF, true));
#else
    return __shfl_xor(x, 1, 64);
#endif
}

// LDS-only barrier (no vmcnt drain — keeps EG prefetch in flight).
__device__ __forceinline__ void lds_barrier() {
    asm volatile("s_waitcnt lgkmcnt(0)" ::: "memory");
    __builtin_amdgcn_s_barrier();
    asm volatile("" ::: "memory");
}

// ---------------------------------------------------------------------------
// Kernel 1: EG gate-bias table, PAIR layout (unchanged, verified):
//   EGp[v][d][p] = float2{ gate rA(p), gate rB(p) },  p in [0,256)
// ---------------------------------------------------------------------------
__global__ __launch_bounds__(256) void eg_gemm(
    const float* __restrict__ emb,
    const float* __restrict__ Wf, const float* __restrict__ bf,
    const float* __restrict__ Wb, const float* __restrict__ bb,
    float* __restrict__ EGp)
{
    __shared__ float As[64][68];
    __shared__ float Bs[64][68];

    const int tid = threadIdx.x;
    const int tx = tid & 15, ty = tid >> 4;
    const int m0 = blockIdx.y * 64;
    const int n0 = blockIdx.x * 64;

    const float* Bsrc;
    const float* bias;
    if (n0 < 512) { Bsrc = Wf + n0 * EE; bias = bf + n0; }
    else          { Bsrc = Wb + (n0 - 512) * EE; bias = bb + (n0 - 512); }

    float acc[4][4] = {};

    for (int kc = 0; kc < 2; ++kc) {
        for (int c = tid; c < 1024; c += 256) {
            int r = c >> 4, q = c & 15;
            float4 av = *(const float4*)(emb + (size_t)(m0 + r) * EE + kc * 64 + q * 4);
            As[q * 4 + 0][r] = av.x; As[q * 4 + 1][r] = av.y;
            As[q * 4 + 2][r] = av.z; As[q * 4 + 3][r] = av.w;
            float4 bv = *(const float4*)(Bsrc + (size_t)r * EE + kc * 64 + q * 4);
            Bs[q * 4 + 0][r] = bv.x; Bs[q * 4 + 1][r] = bv.y;
            Bs[q * 4 + 2][r] = bv.z; Bs[q * 4 + 3][r] = bv.w;
        }
        __syncthreads();
        #pragma unroll 8
        for (int k = 0; k < 64; ++k) {
            float4 a4 = *(const float4*)&As[k][4 * ty];
            float4 b4 = *(const float4*)&Bs[k][4 * tx];
            float a[4] = {a4.x, a4.y, a4.z, a4.w};
            float b[4] = {b4.x, b4.y, b4.z, b4.w};
            #pragma unroll
            for (int i = 0; i < 4; ++i)
                #pragma unroll
                for (int jn = 0; jn < 4; ++jn)
                    acc[i][jn] = fmaf(a[i], b[jn], acc[i][jn]);
        }
        __syncthreads();
    }

    #pragma unroll
    for (int i = 0; i < 4; ++i) {
        int m = m0 + 4 * ty + i;                 // vocab index v
        #pragma unroll
        for (int jn = 0; jn < 4; ++jn) {
            int nn = 4 * tx + jn;
            int n = n0 + nn;                     // combined gate col
            int d = n >> 9;
            int r = n & 511;
            int slot = (r >> 7) & 1;
            int p = (r & 127) + (r >= 256 ? 128 : 0);
            EGp[(((size_t)m * 2 + d) * 256 + p) * 2 + slot] = acc[i][jn] + bias[nn];
        }
    }
}

// ---------------------------------------------------------------------------
// Kernel 2: fused LSTM recurrence + ragged segment max-pool.
//
// Round-20: BOTH directions of one sample in the SAME WAVE's instruction
// stream (grid = 64 blocks, 4 waves, 1 wave/SIMD). Round-19 counters:
// 1402 cy/step, ~273 cy issue, ~1130 cy exposed latency. Round-3/9 showed
// separate-wave co-location gives ZERO overlap (lockstep barrier). Here the
// fwd and bwd chains interleave at INSTRUCTION granularity: chain B's
// independent dots/exps fill chain A's waitcnt shadows; one barrier serves
// both chains' steps. Weights for both dirs = 256 VGPRs (+~50 working,
// <512 at 1 wave/SIMD — watch VGPR_Count for spill).
// Per chain: wave wv owns units [32wv,32wv+32); lane pair (evn) covers
// gates (i,f)/(g,o) as in the verified base. rcp activations, DPP swap,
// distance-2 EG prefetch, LDS-only barrier all retained.
// ---------------------------------------------------------------------------

#define STEP_BOTH(T_, BUF_, XVF_, XVB_, TKF_, TKB_, ISSUE_)                  \
  {                                                                          \
    float2 xvf_ = (XVF_);        /* capture BEFORE in-place reload */        \
    float2 xvb_ = (XVB_);                                                    \
    if (ISSUE_) {                                                            \
      (XVF_) = egp[((size_t)(TKF_) * 2 + 0) * 256 + p];     /* for T_+2 */   \
      (XVB_) = egp[((size_t)(TKB_) * 2 + 1) * 256 + p];                      \
      int i4f_ = max(0, min(TT - 1, (T_) + 4));             /* tok T_+4 */   \
      (TKF_) = srow[i4f_];                                                   \
      int i4b_ = max(0, min(TT - 1, L - 5 - (T_)));                          \
      (TKB_) = srow[i4b_];                                                   \
    }                                                                        \
    float a00f = 0.f, a01f = 0.f, a10f = 0.f, a11f = 0.f;                    \
    float a00b = 0.f, a01b = 0.f, a10b = 0.f, a11b = 0.f;                    \
    _Pragma("unroll")                                                        \
    for (int k4 = 0; k4 < 16; ++k4) {                                        \
      int4 hcf = *(const int4*)&hpkF[BUF_][4 * k4];  /* broadcast b128 */    \
      int4 hcb = *(const int4*)&hpkB[BUF_][4 * k4];                          \
      h2f f0 = __builtin_bit_cast(h2f, hcf.x);                               \
      h2f f1 = __builtin_bit_cast(h2f, hcf.y);                               \
      h2f f2 = __builtin_bit_cast(h2f, hcf.z);                               \
      h2f f3 = __builtin_bit_cast(h2f, hcf.w);                               \
      h2f b0 = __builtin_bit_cast(h2f, hcb.x);                               \
      h2f b1 = __builtin_bit_cast(h2f, hcb.y);                               \
      h2f b2 = __builtin_bit_cast(h2f, hcb.z);                               \
      h2f b3 = __builtin_bit_cast(h2f, hcb.w);                               \
      a00f = dot2acc(w0f[4 * k4 + 0], f0, a00f);                             \
      a00b = dot2acc(w0b[4 * k4 + 0], b0, a00b);                             \
      a10f = dot2acc(w1f[4 * k4 + 0], f0, a10f);                             \
      a10b = dot2acc(w1b[4 * k4 + 0], b0, a10b);                             \
      a01f = dot2acc(w0f[4 * k4 + 1], f1, a01f);                             \
      a01b = dot2acc(w0b[4 * k4 + 1], b1, a01b);                             \
      a11f = dot2acc(w1f[4 * k4 + 1], f1, a11f);                             \
      a11b = dot2acc(w1b[4 * k4 + 1], b1, a11b);                             \
      a00f = dot2acc(w0f[4 * k4 + 2], f2, a00f);                             \
      a00b = dot2acc(w0b[4 * k4 + 2], b2, a00b);                             \
      a10f = dot2acc(w1f[4 * k4 + 2], f2, a10f);                             \
      a10b = dot2acc(w1b[4 * k4 + 2], b2, a10b);                             \
      a01f = dot2acc(w0f[4 * k4 + 3], f3, a01f);                             \
      a01b = dot2acc(w0b[4 * k4 + 3], b3, a01b);                             \
      a11f = dot2acc(w1f[4 * k4 + 3], f3, a11f);                             \
      a11b = dot2acc(w1b[4 * k4 + 3], b3, a11b);                             \
    }                                                                        \
    /* --- fwd gates --- */                                                  \
    float g0f = (a00f + a01f) + xvf_.x;                                      \
    float g1f = (a10f + a11f) + xvf_.y;                                      \
    float sof = sigf(g1f);                                                   \
    float tof = evn ? sigf(g0f) : tanh_fast(g0f);                            \
    /* --- bwd gates (independent; compiler interleaves trans ops) --- */    \
    float g0b = (a00b + a01b) + xvb_.x;                                      \
    float g1b = (a10b + a11b) + xvb_.y;                                      \
    float sob = sigf(g1b);                                                   \
    float tob = evn ? sigf(g0b) : tanh_fast(g0b);                            \
    float txf = xor1_swap(tof);                                              \
    float sxf = xor1_swap(sof);                                              \
    float txb = xor1_swap(tob);                                              \
    float sxb = xor1_swap(sob);                                              \
    cf = sof * cf + tof * txf;                                               \
    cb = sob * cb + tob * txb;                                               \
    float hnf = sxf * tanh_fast(cf);                                         \
    float hnb = sxb * tanh_fast(cb);                                         \
    /* --- fwd pooling --- */                                                \
    {                                                                        \
      bool bnd_ = ((T_) >= nbf);                                             \
      if (bnd_) {                                                            \
        if (evn) {                                                           \
          float v = pmf;                                                     \
          if (haspad && cur_segf >= padlo) v = fmaxf(v, 0.f);                \
          pws[(((size_t)b * 2 + 0) * SS + cur_segf) * H2 + u] = v;           \
        }                                                                    \
        pmf = -INFINITY;                                                     \
        cur_segf += 1;                                                       \
        nbf += wseg;                                                         \
      }                                                                      \
      pmf = fmaxf(pmf, hnf);                                                 \
    }                                                                        \
    /* --- bwd pooling --- */                                                \
    {                                                                        \
      const int ttb_ = L - 1 - (T_);                                         \
      bool bnd_ = (ttb_ < nbb);                                              \
      if (bnd_) {                                                            \
        if (evn) {                                                           \
          float v = pmb;                                                     \
          if (haspad && cur_segb >= padlo) v = fmaxf(v, 0.f);                \
          pws[(((size_t)b * 2 + 1) * SS + cur_segb) * H2 + u] = v;           \
        }                                                                    \
        pmb = -INFINITY;                                                     \
        cur_segb -= 1;                                                       \
        nbb -= wseg;                                                         \
      }                                                                      \
      pmb = fmaxf(pmb, hnb);                                                 \
    }                                                                        \
    if (evn) {                                                               \
      ((_Float16*)hpkF[(BUF_) ^ 1])[u] = (_Float16)hnf;                      \
      ((_Float16*)hpkB[(BUF_) ^ 1])[u] = (_Float16)hnb;                      \
    }                                                                        \
    lds_barrier();                                                           \
  }

__global__ __launch_bounds__(256, 1) void lstm_rec(
    const int* __restrict__ sentence, const int* __restrict__ lens,
    const float* __restrict__ Whhf, const float* __restrict__ Whhb,
    const float* __restrict__ EGp, float* __restrict__ pws)
{
    const int b = blockIdx.x;           // one sample per block (64 blocks)
    const int tid = threadIdx.x;
    const int l = tid & 63;             // lane in wave
    const int wv = tid >> 6;            // wave 0..3
    const int u = wv * 32 + (l >> 1);   // hidden unit this lane pair covers
    const bool evn = (l & 1) == 0;      // even lane: (i,f) + cell state
    const int L = lens[b];
    const int* __restrict__ srow = sentence + (size_t)b * TT;

    // rows of W_hh this lane owns (i/f on even, g/o on odd)
    const int r0 = evn ? u : (256 + u);
    const int r1 = r0 + 128;

    // --- W_hh rows for BOTH dirs -> packed f16 pairs: 256 arch VGPRs ---
    h2f w0f[64], w1f[64], w0b[64], w1b[64];
    #pragma unroll
    for (int k4 = 0; k4 < 32; ++k4) {
        float4 a = *(const float4*)(Whhf + (size_t)r0 * H2 + 4 * k4);
        w0f[2 * k4 + 0].x = (_Float16)a.x; w0f[2 * k4 + 0].y = (_Float16)a.y;
        w0f[2 * k4 + 1].x = (_Float16)a.z; w0f[2 * k4 + 1].y = (_Float16)a.w;
        float4 bq = *(const float4*)(Whhf + (size_t)r1 * H2 + 4 * k4);
        w1f[2 * k4 + 0].x = (_Float16)bq.x; w1f[2 * k4 + 0].y = (_Float16)bq.y;
        w1f[2 * k4 + 1].x = (_Float16)bq.z; w1f[2 * k4 + 1].y = (_Float16)bq.w;
        float4 c4 = *(const float4*)(Whhb + (size_t)r0 * H2 + 4 * k4);
        w0b[2 * k4 + 0].x = (_Float16)c4.x; w0b[2 * k4 + 0].y = (_Float16)c4.y;
        w0b[2 * k4 + 1].x = (_Float16)c4.z; w0b[2 * k4 + 1].y = (_Float16)c4.w;
        float4 d4 = *(const float4*)(Whhb + (size_t)r1 * H2 + 4 * k4);
        w1b[2 * k4 + 0].x = (_Float16)d4.x; w1b[2 * k4 + 0].y = (_Float16)d4.y;
        w1b[2 * k4 + 1].x = (_Float16)d4.z; w1b[2 * k4 + 1].y = (_Float16)d4.w;
    }

    __shared__ __align__(16) int hpk[2][2][64];   // [dir][buf] packed f16 h
    int (*hpkF)[64] = hpk[0];
    int (*hpkB)[64] = hpk[1];
    if (tid < 128) hpk[tid >> 6][0][tid & 63] = 0;

    // per-lane EG pair column
    const int p = evn ? u : (128 + u);
    const float2* __restrict__ egp = (const float2*)EGp;

    float cf = 0.f, cb = 0.f;
    float pmf = -INFINITY, pmb = -INFINITY;

    const int wseg = (L + SS - 1) >> 3;
    const bool haspad = (SS * wseg > L);
    const int padlo = L / wseg;
    int cur_segf = 0,      nbf = wseg;
    int cur_segb = SS - 1, nbb = (SS - 1) * wseg;

    // --- prefetch: EG pairs for t=0,1 (both dirs); tokens for t=2,3 ---
    float2 e0f, e1f, e0b, e1b;
    int tokAf, tokBf, tokAb, tokBb;
    {
        e0f = egp[((size_t)srow[0] * 2 + 0) * 256 + p];
        int j1 = min(TT - 1, 1);
        e1f = egp[((size_t)srow[j1] * 2 + 0) * 256 + p];
        tokAf = srow[max(0, min(TT - 1, 2))];
        tokBf = srow[max(0, min(TT - 1, 3))];

        int j0b = L - 1;
        e0b = egp[((size_t)srow[j0b] * 2 + 1) * 256 + p];
        int j1b = max(0, L - 2);
        e1b = egp[((size_t)srow[j1b] * 2 + 1) * 256 + p];
        tokAb = srow[max(0, L - 3)];
        tokBb = srow[max(0, L - 4)];
    }

    __syncthreads();                    // hpk[*][0] init visible

    int t = 0;
    for (; t + 2 <= L; t += 2) {
        STEP_BOTH(t,     0, e0f, e0b, tokAf, tokAb, true);
        STEP_BOTH(t + 1, 1, e1f, e1b, tokBf, tokBb, true);
    }
    if (t < L) {                        // odd-L tail (t even -> buf 0)
        STEP_BOTH(t, 0, e0f, e0b, tokAf, tokAb, false);
    }

    if (evn) {
        float v = pmf;
        if (haspad && cur_segf >= padlo) v = fmaxf(v, 0.f);
        pws[(((size_t)b * 2 + 0) * SS + cur_segf) * H2 + u] = v;
        v = pmb;
        if (haspad && cur_segb >= padlo) v = fmaxf(v, 0.f);
        pws[(((size_t)b * 2 + 1) * SS + cur_segb) * H2 + u] = v;
    }
}

// ---------------------------------------------------------------------------
// Kernel 3: out[b,c] = b_dense[c] + sum_k flat[b,k] * W_dense[c,k]
// ---------------------------------------------------------------------------
__global__ __launch_bounds__(256) void dense_k(
    const float* __restrict__ pws, const float* __restrict__ Wd,
    const float* __restrict__ bd, float* __restrict__ out)
{
    const int b = blockIdx.x;
    const int tid = threadIdx.x;
    float a0 = 0.f, a1 = 0.f;
    for (int k = tid; k < 2048; k += 256) {
        int h = k >> 3, s = k & 7;
        int dir = h >> 7, j = h & 127;
        float v = pws[(((size_t)b * 2 + dir) * SS + s) * H2 + j];
        a0 = fmaf(v, Wd[k], a0);
        a1 = fmaf(v, Wd[2048 + k], a1);
    }
    __shared__ float r0[256], r1[256];
    r0[tid] = a0; r1[tid] = a1;
    __syncthreads();
    for (int s = 128; s > 0; s >>= 1) {
        if (tid < s) { r0[tid] += r0[tid + s]; r1[tid] += r1[tid + s]; }
        __syncthreads();
    }
    if (tid == 0) {
        out[b * 2 + 0] = r0[0] + bd[0];
        out[b * 2 + 1] = r1[0] + bd[1];
    }
}

// ---------------------------------------------------------------------------
extern "C" void kernel_launch(void* const* d_in, const int* in_sizes, int n_in,
                              void* d_out, int out_size, void* d_ws, size_t ws_size,
                              hipStream_t stream)
{
    const int*   sentence = (const int*)d_in[0];
    const int*   lens     = (const int*)d_in[1];
    const float* emb      = (const float*)d_in[2];
    const float* Wihf     = (const float*)d_in[3];
    const float* Whhf     = (const float*)d_in[4];
    const float* bf       = (const float*)d_in[5];
    const float* Wihb     = (const float*)d_in[6];
    const float* Whhb     = (const float*)d_in[7];
    const float* bb       = (const float*)d_in[8];
    const float* Wd       = (const float*)d_in[9];
    const float* bd       = (const float*)d_in[10];
    float* out = (float*)d_out;

    float* EGp = (float*)d_ws;                    // [4096][2][256][2] fp32 = 16 MB
    float* pws = EGp + (size_t)VV * 1024;         // [64][2][8][128] fp32 = 512 KB

    eg_gemm<<<dim3(16, 64), 256, 0, stream>>>(emb, Wihf, bf, Wihb, bb, EGp);
    lstm_rec<<<64, 256, 0, stream>>>(sentence, lens, Whhf, Whhb, EGp, pws);
    dense_k<<<64, 256, 0, stream>>>(pws, Wd, bd, out);
}

// Round 21
// 1254.519 us; speedup vs baseline: 2.0609x; 2.0609x over previous
//
#include <hip/hip_runtime.h>
#include <hip/hip_bf16.h>
#include <math.h>

// Problem constants (from reference)
#define BB 64
#define TT 2048
#define VV 4096
#define EE 128
#define H2 128
#define SS 8
#define CC 2

typedef _Float16 h2f __attribute__((ext_vector_type(2)));

// v_rcp_f32 instead of precise IEEE divide — round-19 verified win (-10%).
__device__ __forceinline__ float fast_rcp(float x) {
#if __has_builtin(__builtin_amdgcn_rcpf)
    return __builtin_amdgcn_rcpf(x);
#else
    return 1.f / x;
#endif
}

__device__ __forceinline__ float sigf(float x) {
    return fast_rcp(1.f + __expf(-x));
}
__device__ __forceinline__ float tanh_fast(float x) {
    return fmaf(-2.f, fast_rcp(__expf(2.f * x) + 1.f), 1.f);
}

__device__ __forceinline__ float dot2acc(h2f w, h2f h, float acc) {
#if __has_builtin(__builtin_amdgcn_fdot2)
    return __builtin_amdgcn_fdot2(w, h, acc, false);
#else
    return fmaf((float)w.x, (float)h.x, fmaf((float)w.y, (float)h.y, acc));
#endif
}

// lane^1 swap as pure-VALU DPP (quad_perm [1,0,3,2] = ctrl 0xB1).
__device__ __forceinline__ float xor1_swap(float x) {
#if __has_builtin(__builtin_amdgcn_update_dpp)
    return __builtin_bit_cast(float,
        __builtin_amdgcn_update_dpp(0, __builtin_bit_cast(int, x),
                                    0xB1, 0xF, 0xF, true));
#else
    return __shfl_xor(x, 1, 64);
#endif
}

// LDS-only barrier (no vmcnt drain — keeps EG prefetch in flight).
__device__ __forceinline__ void lds_barrier() {
    asm volatile("s_waitcnt lgkmcnt(0)" ::: "memory");
    __builtin_amdgcn_s_barrier();
    asm volatile("" ::: "memory");
}

// ---------------------------------------------------------------------------
// Kernel 1: EG gate-bias table, PAIR layout (unchanged, verified):
//   EGp[v][d][p] = float2{ gate rA(p), gate rB(p) },  p in [0,256)
// ---------------------------------------------------------------------------
__global__ __launch_bounds__(256) void eg_gemm(
    const float* __restrict__ emb,
    const float* __restrict__ Wf, const float* __restrict__ bf,
    const float* __restrict__ Wb, const float* __restrict__ bb,
    float* __restrict__ EGp)
{
    __shared__ float As[64][68];
    __shared__ float Bs[64][68];

    const int tid = threadIdx.x;
    const int tx = tid & 15, ty = tid >> 4;
    const int m0 = blockIdx.y * 64;
    const int n0 = blockIdx.x * 64;

    const float* Bsrc;
    const float* bias;
    if (n0 < 512) { Bsrc = Wf + n0 * EE; bias = bf + n0; }
    else          { Bsrc = Wb + (n0 - 512) * EE; bias = bb + (n0 - 512); }

    float acc[4][4] = {};

    for (int kc = 0; kc < 2; ++kc) {
        for (int c = tid; c < 1024; c += 256) {
            int r = c >> 4, q = c & 15;
            float4 av = *(const float4*)(emb + (size_t)(m0 + r) * EE + kc * 64 + q * 4);
            As[q * 4 + 0][r] = av.x; As[q * 4 + 1][r] = av.y;
            As[q * 4 + 2][r] = av.z; As[q * 4 + 3][r] = av.w;
            float4 bv = *(const float4*)(Bsrc + (size_t)r * EE + kc * 64 + q * 4);
            Bs[q * 4 + 0][r] = bv.x; Bs[q * 4 + 1][r] = bv.y;
            Bs[q * 4 + 2][r] = bv.z; Bs[q * 4 + 3][r] = bv.w;
        }
        __syncthreads();
        #pragma unroll 8
        for (int k = 0; k < 64; ++k) {
            float4 a4 = *(const float4*)&As[k][4 * ty];
            float4 b4 = *(const float4*)&Bs[k][4 * tx];
            float a[4] = {a4.x, a4.y, a4.z, a4.w};
            float b[4] = {b4.x, b4.y, b4.z, b4.w};
            #pragma unroll
            for (int i = 0; i < 4; ++i)
                #pragma unroll
                for (int jn = 0; jn < 4; ++jn)
                    acc[i][jn] = fmaf(a[i], b[jn], acc[i][jn]);
        }
        __syncthreads();
    }

    #pragma unroll
    for (int i = 0; i < 4; ++i) {
        int m = m0 + 4 * ty + i;                 // vocab index v
        #pragma unroll
        for (int jn = 0; jn < 4; ++jn) {
            int nn = 4 * tx + jn;
            int n = n0 + nn;                     // combined gate col
            int d = n >> 9;
            int r = n & 511;
            int slot = (r >> 7) & 1;
            int p = (r & 127) + (r >= 256 ? 128 : 0);
            EGp[(((size_t)m * 2 + d) * 256 + p) * 2 + slot] = acc[i][jn] + bias[nn];
        }
    }
}

// ---------------------------------------------------------------------------
// Kernel 2: fused LSTM recurrence + ragged segment max-pool.
// Base = round-19 measured best (1197 us lstm_rec): grid = 128 blocks
// (b,dir), 4 waves, 1 wave/SIMD; broadcast ds_read_b128 h; DPP gate
// exchange; rcp activations; distance-2 EG prefetch; LDS-only barrier.
//
// Round-20 lesson: dual-chain-per-wave needs ~310 VGPR -> AGPR shuffling,
// 2.1x regression. Register file caps ILP at one chain/wave. Reverted.
//
// Round-21 (this): two latency cuts on the same structure:
//  1. dot loop split 4 -> 8 accumulator chains (16-deep, strictly
//     issue-bound; removes dependent-latency tail).
//  2. h publish (cvt+ds_write) moved IMMEDIATELY after hn, before pooling
//     bookkeeping — the write drains during pooling instead of delaying
//     the pre-barrier lgkmcnt(0) wait of all 4 waves.
// ---------------------------------------------------------------------------

#define LSTM_STEP(T_, BUF_, XV_, TOKN_, ISSUE_)                              \
  {                                                                          \
    float2 xv_ = (XV_);          /* capture BEFORE in-place reload */        \
    if (ISSUE_) {                                                            \
      (XV_) = egp[((size_t)(TOKN_) * 2 + dir) * 256 + p];   /* for T_+2 */   \
      int i4_ = dir ? (L - 5 - (T_)) : ((T_) + 4);          /* tok T_+4 */   \
      i4_ = max(0, min(TT - 1, i4_));                                        \
      (TOKN_) = srow[i4_];                                                   \
    }                                                                        \
    float p00 = 0.f, p01 = 0.f, p10 = 0.f, p11 = 0.f;                        \
    float q00 = 0.f, q01 = 0.f, q10 = 0.f, q11 = 0.f;                        \
    _Pragma("unroll")                                                        \
    for (int k8 = 0; k8 < 8; ++k8) {                                         \
      int4 hc0 = *(const int4*)&hpk[BUF_][8 * k8 + 0];  /* broadcast */      \
      int4 hc1 = *(const int4*)&hpk[BUF_][8 * k8 + 4];                       \
      h2f a0 = __builtin_bit_cast(h2f, hc0.x);                               \
      h2f a1 = __builtin_bit_cast(h2f, hc0.y);                               \
      h2f a2 = __builtin_bit_cast(h2f, hc0.z);                               \
      h2f a3 = __builtin_bit_cast(h2f, hc0.w);                               \
      h2f b0 = __builtin_bit_cast(h2f, hc1.x);                               \
      h2f b1 = __builtin_bit_cast(h2f, hc1.y);                               \
      h2f b2 = __builtin_bit_cast(h2f, hc1.z);                               \
      h2f b3 = __builtin_bit_cast(h2f, hc1.w);                               \
      p00 = dot2acc(w0[8 * k8 + 0], a0, p00);                                \
      q00 = dot2acc(w0[8 * k8 + 4], b0, q00);                                \
      p10 = dot2acc(w1[8 * k8 + 0], a0, p10);                                \
      q10 = dot2acc(w1[8 * k8 + 4], b0, q10);                                \
      p01 = dot2acc(w0[8 * k8 + 1], a1, p01);                                \
      q01 = dot2acc(w0[8 * k8 + 5], b1, q01);                                \
      p11 = dot2acc(w1[8 * k8 + 1], a1, p11);                                \
      q11 = dot2acc(w1[8 * k8 + 5], b1, q11);                                \
      p00 = dot2acc(w0[8 * k8 + 2], a2, p00);                                \
      q00 = dot2acc(w0[8 * k8 + 6], b2, q00);                                \
      p10 = dot2acc(w1[8 * k8 + 2], a2, p10);                                \
      q10 = dot2acc(w1[8 * k8 + 6], b2, q10);                                \
      p01 = dot2acc(w0[8 * k8 + 3], a3, p01);                                \
      q01 = dot2acc(w0[8 * k8 + 7], b3, q01);                                \
      p11 = dot2acc(w1[8 * k8 + 3], a3, p11);                                \
      q11 = dot2acc(w1[8 * k8 + 7], b3, q11);                                \
    }                                                                        \
    float g0 = ((p00 + p01) + (q00 + q01)) + xv_.x;  /* i | g preact */      \
    float g1 = ((p10 + p11) + (q10 + q11)) + xv_.y;  /* f | o preact */      \
    float s_own = sigf(g1);                            /* sf | so */         \
    float t_own = evn ? sigf(g0) : tanh_fast(g0);      /* si | tg */         \
    float t_x = xor1_swap(t_own);                                            \
    float s_x = xor1_swap(s_own);                                            \
    c = s_own * c + t_own * t_x;                                             \
    float hn = s_x * tanh_fast(c);                                           \
    /* publish FIRST: write drains while pooling bookkeeping runs */         \
    if (evn) ((_Float16*)hpk[(BUF_) ^ 1])[u] = (_Float16)hn;                 \
    const int tt_ = dir ? (L - 1 - (T_)) : (T_);                             \
    bool bnd_ = dir ? (tt_ < nb) : (tt_ >= nb);                              \
    if (bnd_) {                                                              \
      if (evn) {                                                             \
        float v = pm;                                                        \
        if (haspad && cur_seg >= padlo) v = fmaxf(v, 0.f);                   \
        pws[(((size_t)b * 2 + dir) * SS + cur_seg) * H2 + u] = v;            \
      }                                                                      \
      pm = -INFINITY;                                                        \
      cur_seg += dir ? -1 : 1;                                               \
      nb += dir ? -wseg : wseg;                                              \
    }                                                                        \
    pm = fmaxf(pm, hn);                                                      \
    lds_barrier();                                                           \
  }

__global__ __launch_bounds__(256, 1) void lstm_rec(
    const int* __restrict__ sentence, const int* __restrict__ lens,
    const float* __restrict__ Whhf, const float* __restrict__ Whhb,
    const float* __restrict__ EGp, float* __restrict__ pws)
{
    const int bid = blockIdx.x;
    const int b = bid >> 1;
    const int dir = bid & 1;            // 0 = forward, 1 = backward
    const int tid = threadIdx.x;
    const int l = tid & 63;             // lane in wave
    const int wv = tid >> 6;            // wave 0..3
    const int u = wv * 32 + (l >> 1);   // hidden unit this lane pair covers
    const bool evn = (l & 1) == 0;      // even lane: (i,f) + cell state
    const int L = lens[b];
    const int* __restrict__ srow = sentence + (size_t)b * TT;

    // rows of W_hh this lane owns (i/f on even, g/o on odd)
    const int r0 = evn ? u : (256 + u);
    const int r1 = r0 + 128;
    const float* __restrict__ Wh = (dir == 0 ? Whhf : Whhb);

    // --- W_hh rows -> packed f16 pairs: 128 arch VGPRs ---
    h2f w0[64], w1[64];
    #pragma unroll
    for (int k4 = 0; k4 < 32; ++k4) {
        float4 a = *(const float4*)(Wh + (size_t)r0 * H2 + 4 * k4);
        w0[2 * k4 + 0].x = (_Float16)a.x; w0[2 * k4 + 0].y = (_Float16)a.y;
        w0[2 * k4 + 1].x = (_Float16)a.z; w0[2 * k4 + 1].y = (_Float16)a.w;
        float4 bq = *(const float4*)(Wh + (size_t)r1 * H2 + 4 * k4);
        w1[2 * k4 + 0].x = (_Float16)bq.x; w1[2 * k4 + 0].y = (_Float16)bq.y;
        w1[2 * k4 + 1].x = (_Float16)bq.z; w1[2 * k4 + 1].y = (_Float16)bq.w;
    }

    __shared__ __align__(16) int hpk[2][64];   // double-buffered packed f16 h pairs
    if (tid < 64) hpk[0][tid] = 0;

    // per-lane EG pair column
    const int p = evn ? u : (128 + u);
    const float2* __restrict__ egp = (const float2*)EGp;
    // element index for token v: (v*2+dir)*256 + p

    float c = 0.f;
    float pm = -INFINITY;

    const int wseg = (L + SS - 1) >> 3;
    const bool haspad = (SS * wseg > L);
    const int padlo = L / wseg;
    int cur_seg = dir ? (SS - 1) : 0;
    int nb = dir ? (SS - 1) * wseg : wseg;

    // --- prefetch pipeline: EG pairs for t=0,1 in flight; tokens for t=2,3 staged ---
    float2 e0, e1;
    int tokA, tokB;
    {
        int j0 = dir ? (L - 1) : 0;
        e0 = egp[((size_t)srow[j0] * 2 + dir) * 256 + p];
        int j1 = dir ? (L - 2) : 1;  j1 = max(0, min(TT - 1, j1));
        e1 = egp[((size_t)srow[j1] * 2 + dir) * 256 + p];
        int j2 = dir ? (L - 3) : 2;  j2 = max(0, min(TT - 1, j2));
        tokA = srow[j2];
        int j3 = dir ? (L - 4) : 3;  j3 = max(0, min(TT - 1, j3));
        tokB = srow[j3];
    }

    __syncthreads();                    // hpk[0] init visible (full drain ok here)

    int t = 0;
    for (; t + 2 <= L; t += 2) {
        LSTM_STEP(t,     0, e0, tokA, true);
        LSTM_STEP(t + 1, 1, e1, tokB, true);
    }
    if (t < L) {                        // odd-L tail (t even -> buf 0)
        LSTM_STEP(t, 0, e0, tokA, false);
    }

    if (evn) {
        float v = pm;
        if (haspad && cur_seg >= padlo) v = fmaxf(v, 0.f);
        pws[(((size_t)b * 2 + dir) * SS + cur_seg) * H2 + u] = v;
    }
}

// ---------------------------------------------------------------------------
// Kernel 3: out[b,c] = b_dense[c] + sum_k flat[b,k] * W_dense[c,k]
// ---------------------------------------------------------------------------
__global__ __launch_bounds__(256) void dense_k(
    const float* __restrict__ pws, const float* __restrict__ Wd,
    const float* __restrict__ bd, float* __restrict__ out)
{
    const int b = blockIdx.x;
    const int tid = threadIdx.x;
    float a0 = 0.f, a1 = 0.f;
    for (int k = tid; k < 2048; k += 256) {
        int h = k >> 3, s = k & 7;
        int dir = h >> 7, j = h & 127;
        float v = pws[(((size_t)b * 2 + dir) * SS + s) * H2 + j];
        a0 = fmaf(v, Wd[k], a0);
        a1 = fmaf(v, Wd[2048 + k], a1);
    }
    __shared__ float r0[256], r1[256];
    r0[tid] = a0; r1[tid] = a1;
    __syncthreads();
    for (int s = 128; s > 0; s >>= 1) {
        if (tid < s) { r0[tid] += r0[tid + s]; r1[tid] += r1[tid + s]; }
        __syncthreads();
    }
    if (tid == 0) {
        out[b * 2 + 0] = r0[0] + bd[0];
        out[b * 2 + 1] = r1[0] + bd[1];
    }
}

// ---------------------------------------------------------------------------
extern "C" void kernel_launch(void* const* d_in, const int* in_sizes, int n_in,
                              void* d_out, int out_size, void* d_ws, size_t ws_size,
                              hipStream_t stream)
{
    const int*   sentence = (const int*)d_in[0];
    const int*   lens     = (const int*)d_in[1];
    const float* emb      = (const float*)d_in[2];
    const float* Wihf     = (const float*)d_in[3];
    const float* Whhf     = (const float*)d_in[4];
    const float* bf       = (const float*)d_in[5];
    const float* Wihb     = (const float*)d_in[6];
    const float* Whhb     = (const float*)d_in[7];
    const float* bb       = (const float*)d_in[8];
    const float* Wd       = (const float*)d_in[9];
    const float* bd       = (const float*)d_in[10];
    float* out = (float*)d_out;

    float* EGp = (float*)d_ws;                    // [4096][2][256][2] fp32 = 16 MB
    float* pws = EGp + (size_t)VV * 1024;         // [64][2][8][128] fp32 = 512 KB

    eg_gemm<<<dim3(16, 64), 256, 0, stream>>>(emb, Wihf, bf, Wihb, bb, EGp);
    lstm_rec<<<128, 256, 0, stream>>>(sentence, lens, Whhf, Whhb, EGp, pws);
    dense_k<<<64, 256, 0, stream>>>(pws, Wd, bd, out);
}

// Round 22
// 1225.307 us; speedup vs baseline: 2.1100x; 1.0238x over previous
//
#include <hip/hip_runtime.h>
#include <hip/hip_bf16.h>
#include <math.h>

// Problem constants (from reference)
#define BB 64
#define TT 2048
#define VV 4096
#define EE 128
#define H2 128
#define SS 8
#define CC 2

typedef _Float16 h2f __attribute__((ext_vector_type(2)));

// v_rcp_f32 instead of precise IEEE divide — round-19 verified win (-10%).
__device__ __forceinline__ float fast_rcp(float x) {
#if __has_builtin(__builtin_amdgcn_rcpf)
    return __builtin_amdgcn_rcpf(x);
#else
    return 1.f / x;
#endif
}

__device__ __forceinline__ float sigf(float x) {
    return fast_rcp(1.f + __expf(-x));
}
__device__ __forceinline__ float tanh_fast(float x) {
    return fmaf(-2.f, fast_rcp(__expf(2.f * x) + 1.f), 1.f);
}

__device__ __forceinline__ float dot2acc(h2f w, h2f h, float acc) {
#if __has_builtin(__builtin_amdgcn_fdot2)
    return __builtin_amdgcn_fdot2(w, h, acc, false);
#else
    return fmaf((float)w.x, (float)h.x, fmaf((float)w.y, (float)h.y, acc));
#endif
}

// lane^1 swap as pure-VALU DPP (quad_perm [1,0,3,2] = ctrl 0xB1).
__device__ __forceinline__ float xor1_swap(float x) {
#if __has_builtin(__builtin_amdgcn_update_dpp)
    return __builtin_bit_cast(float,
        __builtin_amdgcn_update_dpp(0, __builtin_bit_cast(int, x),
                                    0xB1, 0xF, 0xF, true));
#else
    return __shfl_xor(x, 1, 64);
#endif
}

// LDS-only barrier (no vmcnt drain — keeps EG prefetch in flight).
__device__ __forceinline__ void lds_barrier() {
    asm volatile("s_waitcnt lgkmcnt(0)" ::: "memory");
    __builtin_amdgcn_s_barrier();
    asm volatile("" ::: "memory");
}

// ---------------------------------------------------------------------------
// Kernel 1: EG gate-bias table, PAIR layout (unchanged, verified):
//   EGp[v][d][p] = float2{ gate rA(p), gate rB(p) },  p in [0,256)
// ---------------------------------------------------------------------------
__global__ __launch_bounds__(256) void eg_gemm(
    const float* __restrict__ emb,
    const float* __restrict__ Wf, const float* __restrict__ bf,
    const float* __restrict__ Wb, const float* __restrict__ bb,
    float* __restrict__ EGp)
{
    __shared__ float As[64][68];
    __shared__ float Bs[64][68];

    const int tid = threadIdx.x;
    const int tx = tid & 15, ty = tid >> 4;
    const int m0 = blockIdx.y * 64;
    const int n0 = blockIdx.x * 64;

    const float* Bsrc;
    const float* bias;
    if (n0 < 512) { Bsrc = Wf + n0 * EE; bias = bf + n0; }
    else          { Bsrc = Wb + (n0 - 512) * EE; bias = bb + (n0 - 512); }

    float acc[4][4] = {};

    for (int kc = 0; kc < 2; ++kc) {
        for (int c = tid; c < 1024; c += 256) {
            int r = c >> 4, q = c & 15;
            float4 av = *(const float4*)(emb + (size_t)(m0 + r) * EE + kc * 64 + q * 4);
            As[q * 4 + 0][r] = av.x; As[q * 4 + 1][r] = av.y;
            As[q * 4 + 2][r] = av.z; As[q * 4 + 3][r] = av.w;
            float4 bv = *(const float4*)(Bsrc + (size_t)r * EE + kc * 64 + q * 4);
            Bs[q * 4 + 0][r] = bv.x; Bs[q * 4 + 1][r] = bv.y;
            Bs[q * 4 + 2][r] = bv.z; Bs[q * 4 + 3][r] = bv.w;
        }
        __syncthreads();
        #pragma unroll 8
        for (int k = 0; k < 64; ++k) {
            float4 a4 = *(const float4*)&As[k][4 * ty];
            float4 b4 = *(const float4*)&Bs[k][4 * tx];
            float a[4] = {a4.x, a4.y, a4.z, a4.w};
            float b[4] = {b4.x, b4.y, b4.z, b4.w};
            #pragma unroll
            for (int i = 0; i < 4; ++i)
                #pragma unroll
                for (int jn = 0; jn < 4; ++jn)
                    acc[i][jn] = fmaf(a[i], b[jn], acc[i][jn]);
        }
        __syncthreads();
    }

    #pragma unroll
    for (int i = 0; i < 4; ++i) {
        int m = m0 + 4 * ty + i;                 // vocab index v
        #pragma unroll
        for (int jn = 0; jn < 4; ++jn) {
            int nn = 4 * tx + jn;
            int n = n0 + nn;                     // combined gate col
            int d = n >> 9;
            int r = n & 511;
            int slot = (r >> 7) & 1;
            int p = (r & 127) + (r >= 256 ? 128 : 0);
            EGp[(((size_t)m * 2 + d) * 256 + p) * 2 + slot] = acc[i][jn] + bias[nn];
        }
    }
}

// ---------------------------------------------------------------------------
// Kernel 2: fused LSTM recurrence + ragged segment max-pool.
// Base = round-21 (1178 us lstm_rec): grid = 128 blocks (b,dir), 4 waves,
// 1 wave/SIMD; DPP gate exchange; rcp activations; distance-2 EG prefetch;
// LDS-only barrier; publish-before-pooling.
//
// Round-22 (this): K-SPLIT to halve LDS read traffic. Accounting showed
// ~1100 cy/step non-issue; candidate: 4 waves x 16 ds_read_b128 = 64
// b128/CU/step through one LDS pipe at ~12 cy (m134) = 768 cy — the pipe,
// not VALU, is the bottleneck. Change: each lane loads ALL 4 gate rows of
// its unit restricted to its k-half (even: k<64, odd: k>=64) -> 8 b128
// reads/lane (was 16), same 128 dot2, same 128 weight VGPRs. Partial sums
// completed with 4 DPP xor1 swaps + adds. Downstream identical.
// ---------------------------------------------------------------------------

#define LSTM_STEP(T_, BUF_, XV_, TOKN_, ISSUE_)                              \
  {                                                                          \
    float2 xv_ = (XV_);          /* capture BEFORE in-place reload */        \
    if (ISSUE_) {                                                            \
      (XV_) = egp[((size_t)(TOKN_) * 2 + dir) * 256 + p];   /* for T_+2 */   \
      int i4_ = dir ? (L - 5 - (T_)) : ((T_) + 4);          /* tok T_+4 */   \
      i4_ = max(0, min(TT - 1, i4_));                                        \
      (TOKN_) = srow[i4_];                                                   \
    }                                                                        \
    float c0a = 0.f, c1a = 0.f, c2a = 0.f, c3a = 0.f;                        \
    float c0b = 0.f, c1b = 0.f, c2b = 0.f, c3b = 0.f;                        \
    const int4* hb4 = (const int4*)&hpk[BUF_][hoff];                         \
    _Pragma("unroll")                                                        \
    for (int k8 = 0; k8 < 8; k8 += 2) {                                      \
      int4 u0 = hb4[k8];                                                     \
      int4 u1 = hb4[k8 + 1];                                                 \
      h2f h0 = __builtin_bit_cast(h2f, u0.x);                                \
      h2f h1 = __builtin_bit_cast(h2f, u0.y);                                \
      h2f h2 = __builtin_bit_cast(h2f, u0.z);                                \
      h2f h3 = __builtin_bit_cast(h2f, u0.w);                                \
      h2f h4 = __builtin_bit_cast(h2f, u1.x);                                \
      h2f h5 = __builtin_bit_cast(h2f, u1.y);                                \
      h2f h6 = __builtin_bit_cast(h2f, u1.z);                                \
      h2f h7 = __builtin_bit_cast(h2f, u1.w);                                \
      c0a = dot2acc(wg[0][4 * k8 + 0], h0, c0a);                             \
      c1a = dot2acc(wg[1][4 * k8 + 0], h0, c1a);                             \
      c2a = dot2acc(wg[2][4 * k8 + 0], h0, c2a);                             \
      c3a = dot2acc(wg[3][4 * k8 + 0], h0, c3a);                             \
      c0b = dot2acc(wg[0][4 * k8 + 4], h4, c0b);                             \
      c1b = dot2acc(wg[1][4 * k8 + 4], h4, c1b);                             \
      c2b = dot2acc(wg[2][4 * k8 + 4], h4, c2b);                             \
      c3b = dot2acc(wg[3][4 * k8 + 4], h4, c3b);                             \
      c0a = dot2acc(wg[0][4 * k8 + 1], h1, c0a);                             \
      c1a = dot2acc(wg[1][4 * k8 + 1], h1, c1a);                             \
      c2a = dot2acc(wg[2][4 * k8 + 1], h1, c2a);                             \
      c3a = dot2acc(wg[3][4 * k8 + 1], h1, c3a);                             \
      c0b = dot2acc(wg[0][4 * k8 + 5], h5, c0b);                             \
      c1b = dot2acc(wg[1][4 * k8 + 5], h5, c1b);                             \
      c2b = dot2acc(wg[2][4 * k8 + 5], h5, c2b);                             \
      c3b = dot2acc(wg[3][4 * k8 + 5], h5, c3b);                             \
      c0a = dot2acc(wg[0][4 * k8 + 2], h2, c0a);                             \
      c1a = dot2acc(wg[1][4 * k8 + 2], h2, c1a);                             \
      c2a = dot2acc(wg[2][4 * k8 + 2], h2, c2a);                             \
      c3a = dot2acc(wg[3][4 * k8 + 2], h2, c3a);                             \
      c0b = dot2acc(wg[0][4 * k8 + 6], h6, c0b);                             \
      c1b = dot2acc(wg[1][4 * k8 + 6], h6, c1b);                             \
      c2b = dot2acc(wg[2][4 * k8 + 6], h6, c2b);                             \
      c3b = dot2acc(wg[3][4 * k8 + 6], h6, c3b);                             \
      c0a = dot2acc(wg[0][4 * k8 + 3], h3, c0a);                             \
      c1a = dot2acc(wg[1][4 * k8 + 3], h3, c1a);                             \
      c2a = dot2acc(wg[2][4 * k8 + 3], h3, c2a);                             \
      c3a = dot2acc(wg[3][4 * k8 + 3], h3, c3a);                             \
      c0b = dot2acc(wg[0][4 * k8 + 7], h7, c0b);                             \
      c1b = dot2acc(wg[1][4 * k8 + 7], h7, c1b);                             \
      c2b = dot2acc(wg[2][4 * k8 + 7], h7, c2b);                             \
      c3b = dot2acc(wg[3][4 * k8 + 7], h7, c3b);                             \
    }                                                                        \
    float o0 = c0a + c0b;   /* partial i-preact (own k-half) */              \
    float o1 = c1a + c1b;   /* partial f-preact */                           \
    float o2 = c2a + c2b;   /* partial g-preact */                           \
    float o3 = c3a + c3b;   /* partial o-preact */                           \
    float x0 = xor1_swap(o0);                                                \
    float x1 = xor1_swap(o1);                                                \
    float x2 = xor1_swap(o2);                                                \
    float x3 = xor1_swap(o3);                                                \
    float g0 = (evn ? (o0 + x0) : (o2 + x2)) + xv_.x;  /* i | g preact */    \
    float g1 = (evn ? (o1 + x1) : (o3 + x3)) + xv_.y;  /* f | o preact */    \
    float s_own = sigf(g1);                            /* sf | so */         \
    float t_own = evn ? sigf(g0) : tanh_fast(g0);      /* si | tg */         \
    float t_x = xor1_swap(t_own);                                            \
    float s_x = xor1_swap(s_own);                                            \
    c = s_own * c + t_own * t_x;                                             \
    float hn = s_x * tanh_fast(c);                                           \
    /* publish FIRST: write drains while pooling bookkeeping runs */         \
    if (evn) ((_Float16*)hpk[(BUF_) ^ 1])[u] = (_Float16)hn;                 \
    const int tt_ = dir ? (L - 1 - (T_)) : (T_);                             \
    bool bnd_ = dir ? (tt_ < nb) : (tt_ >= nb);                              \
    if (bnd_) {                                                              \
      if (evn) {                                                             \
        float v = pm;                                                        \
        if (haspad && cur_seg >= padlo) v = fmaxf(v, 0.f);                   \
        pws[(((size_t)b * 2 + dir) * SS + cur_seg) * H2 + u] = v;            \
      }                                                                      \
      pm = -INFINITY;                                                        \
      cur_seg += dir ? -1 : 1;                                               \
      nb += dir ? -wseg : wseg;                                              \
    }                                                                        \
    pm = fmaxf(pm, hn);                                                      \
    lds_barrier();                                                           \
  }

__global__ __launch_bounds__(256, 1) void lstm_rec(
    const int* __restrict__ sentence, const int* __restrict__ lens,
    const float* __restrict__ Whhf, const float* __restrict__ Whhb,
    const float* __restrict__ EGp, float* __restrict__ pws)
{
    const int bid = blockIdx.x;
    const int b = bid >> 1;
    const int dir = bid & 1;            // 0 = forward, 1 = backward
    const int tid = threadIdx.x;
    const int l = tid & 63;             // lane in wave
    const int wv = tid >> 6;            // wave 0..3
    const int u = wv * 32 + (l >> 1);   // hidden unit this lane pair covers
    const bool evn = (l & 1) == 0;      // even lane: (i,f) + cell state
    const int L = lens[b];
    const int* __restrict__ srow = sentence + (size_t)b * TT;
    const float* __restrict__ Wh = (dir == 0 ? Whhf : Whhb);

    // k-half this lane covers: even k in [0,64), odd k in [64,128)
    const int kb = evn ? 0 : 64;
    const int hoff = evn ? 0 : 32;      // int offset into hpk row (64 f16 = 32 ints)

    // --- W_hh: ALL 4 gate rows of unit u, own k-half. 128 VGPRs. ---
    // wg[g] = row (g*128 + u), k in [kb, kb+64), packed f16 pairs.
    h2f wg[4][32];
    #pragma unroll
    for (int g = 0; g < 4; ++g) {
        const float* src = Wh + (size_t)(g * 128 + u) * H2 + kb;
        #pragma unroll
        for (int k4 = 0; k4 < 16; ++k4) {
            float4 a = *(const float4*)(src + 4 * k4);
            wg[g][2 * k4 + 0].x = (_Float16)a.x;
            wg[g][2 * k4 + 0].y = (_Float16)a.y;
            wg[g][2 * k4 + 1].x = (_Float16)a.z;
            wg[g][2 * k4 + 1].y = (_Float16)a.w;
        }
    }

    __shared__ __align__(16) int hpk[2][64];   // double-buffered packed f16 h pairs
    if (tid < 64) hpk[0][tid] = 0;

    // per-lane EG pair column (even: (i,f) of u ; odd: (g,o) of u)
    const int p = evn ? u : (128 + u);
    const float2* __restrict__ egp = (const float2*)EGp;

    float c = 0.f;
    float pm = -INFINITY;

    const int wseg = (L + SS - 1) >> 3;
    const bool haspad = (SS * wseg > L);
    const int padlo = L / wseg;
    int cur_seg = dir ? (SS - 1) : 0;
    int nb = dir ? (SS - 1) * wseg : wseg;

    // --- prefetch pipeline: EG pairs for t=0,1 in flight; tokens for t=2,3 staged ---
    float2 e0, e1;
    int tokA, tokB;
    {
        int j0 = dir ? (L - 1) : 0;
        e0 = egp[((size_t)srow[j0] * 2 + dir) * 256 + p];
        int j1 = dir ? (L - 2) : 1;  j1 = max(0, min(TT - 1, j1));
        e1 = egp[((size_t)srow[j1] * 2 + dir) * 256 + p];
        int j2 = dir ? (L - 3) : 2;  j2 = max(0, min(TT - 1, j2));
        tokA = srow[j2];
        int j3 = dir ? (L - 4) : 3;  j3 = max(0, min(TT - 1, j3));
        tokB = srow[j3];
    }

    __syncthreads();                    // hpk[0] init visible (full drain ok here)

    int t = 0;
    for (; t + 2 <= L; t += 2) {
        LSTM_STEP(t,     0, e0, tokA, true);
        LSTM_STEP(t + 1, 1, e1, tokB, true);
    }
    if (t < L) {                        // odd-L tail (t even -> buf 0)
        LSTM_STEP(t, 0, e0, tokA, false);
    }

    if (evn) {
        float v = pm;
        if (haspad && cur_seg >= padlo) v = fmaxf(v, 0.f);
        pws[(((size_t)b * 2 + dir) * SS + cur_seg) * H2 + u] = v;
    }
}

// ---------------------------------------------------------------------------
// Kernel 3: out[b,c] = b_dense[c] + sum_k flat[b,k] * W_dense[c,k]
// ---------------------------------------------------------------------------
__global__ __launch_bounds__(256) void dense_k(
    const float* __restrict__ pws, const float* __restrict__ Wd,
    const float* __restrict__ bd, float* __restrict__ out)
{
    const int b = blockIdx.x;
    const int tid = threadIdx.x;
    float a0 = 0.f, a1 = 0.f;
    for (int k = tid; k < 2048; k += 256) {
        int h = k >> 3, s = k & 7;
        int dir = h >> 7, j = h & 127;
        float v = pws[(((size_t)b * 2 + dir) * SS + s) * H2 + j];
        a0 = fmaf(v, Wd[k], a0);
        a1 = fmaf(v, Wd[2048 + k], a1);
    }
    __shared__ float r0[256], r1[256];
    r0[tid] = a0; r1[tid] = a1;
    __syncthreads();
    for (int s = 128; s > 0; s >>= 1) {
        if (tid < s) { r0[tid] += r0[tid + s]; r1[tid] += r1[tid + s]; }
        __syncthreads();
    }
    if (tid == 0) {
        out[b * 2 + 0] = r0[0] + bd[0];
        out[b * 2 + 1] = r1[0] + bd[1];
    }
}

// ---------------------------------------------------------------------------
extern "C" void kernel_launch(void* const* d_in, const int* in_sizes, int n_in,
                              void* d_out, int out_size, void* d_ws, size_t ws_size,
                              hipStream_t stream)
{
    const int*   sentence = (const int*)d_in[0];
    const int*   lens     = (const int*)d_in[1];
    const float* emb      = (const float*)d_in[2];
    const float* Wihf     = (const float*)d_in[3];
    const float* Whhf     = (const float*)d_in[4];
    const float* bf       = (const float*)d_in[5];
    const float* Wihb     = (const float*)d_in[6];
    const float* Whhb     = (const float*)d_in[7];
    const float* bb       = (const float*)d_in[8];
    const float* Wd       = (const float*)d_in[9];
    const float* bd       = (const float*)d_in[10];
    float* out = (float*)d_out;

    float* EGp = (float*)d_ws;                    // [4096][2][256][2] fp32 = 16 MB
    float* pws = EGp + (size_t)VV * 1024;         // [64][2][8][128] fp32 = 512 KB

    eg_gemm<<<dim3(16, 64), 256, 0, stream>>>(emb, Wihf, bf, Wihb, bb, EGp);
    lstm_rec<<<128, 256, 0, stream>>>(sentence, lens, Whhf, Whhb, EGp, pws);
    dense_k<<<64, 256, 0, stream>>>(pws, Wd, bd, out);
}

// Round 23
// 1218.493 us; speedup vs baseline: 2.1218x; 1.0056x over previous
//
#include <hip/hip_runtime.h>
#include <hip/hip_bf16.h>
#include <math.h>

// Problem constants (from reference)
#define BB 64
#define TT 2048
#define VV 4096
#define EE 128
#define H2 128
#define SS 8
#define CC 2

#define L2E  1.44269504f      // log2(e)
#define L2E2 2.88539008f      // 2*log2(e)

typedef _Float16 h2f __attribute__((ext_vector_type(2)));

// v_rcp_f32 instead of precise IEEE divide — round-19 verified win (-10%).
__device__ __forceinline__ float fast_rcp(float x) {
#if __has_builtin(__builtin_amdgcn_rcpf)
    return __builtin_amdgcn_rcpf(x);
#else
    return 1.f / x;
#endif
}

__device__ __forceinline__ float exp2_fast(float x) {
#if __has_builtin(__builtin_amdgcn_exp2f)
    return __builtin_amdgcn_exp2f(x);
#else
    return __exp2f(x);
#endif
}

// Round-23: preacts are pre-scaled by log2e (gates i,f,o) / 2*log2e (gate g)
// via the weights and EG table, so activations need NO leading v_mul —
// the mul sat on the serial path before every v_exp.
__device__ __forceinline__ float sig2(float y) {          // y = x*log2e
    return fast_rcp(1.f + exp2_fast(-y));
}
__device__ __forceinline__ float tanh2(float y) {         // y = x*2*log2e
    return fmaf(-2.f, fast_rcp(exp2_fast(y) + 1.f), 1.f);
}
__device__ __forceinline__ float tanh_c(float c) {        // c unscaled
    return fmaf(-2.f, fast_rcp(exp2_fast(c * L2E2) + 1.f), 1.f);
}

__device__ __forceinline__ float dot2acc(h2f w, h2f h, float acc) {
#if __has_builtin(__builtin_amdgcn_fdot2)
    return __builtin_amdgcn_fdot2(w, h, acc, false);
#else
    return fmaf((float)w.x, (float)h.x, fmaf((float)w.y, (float)h.y, acc));
#endif
}

// lane^1 swap as pure-VALU DPP (quad_perm [1,0,3,2] = ctrl 0xB1).
__device__ __forceinline__ float xor1_swap(float x) {
#if __has_builtin(__builtin_amdgcn_update_dpp)
    return __builtin_bit_cast(float,
        __builtin_amdgcn_update_dpp(0, __builtin_bit_cast(int, x),
                                    0xB1, 0xF, 0xF, true));
#else
    return __shfl_xor(x, 1, 64);
#endif
}

// LDS-only barrier (no vmcnt drain — keeps EG prefetch in flight).
__device__ __forceinline__ void lds_barrier() {
    asm volatile("s_waitcnt lgkmcnt(0)" ::: "memory");
    __builtin_amdgcn_s_barrier();
    asm volatile("" ::: "memory");
}

// ---------------------------------------------------------------------------
// Kernel 1: EG gate-bias table, PAIR layout. Round-23: values PRE-SCALED by
// log2e (gates i,f,o) or 2*log2e (gate g) so lstm_rec activations skip the
// exp pre-multiply. Gate id = r>>7 (0:i 1:f 2:g 3:o).
// ---------------------------------------------------------------------------
__global__ __launch_bounds__(256) void eg_gemm(
    const float* __restrict__ emb,
    const float* __restrict__ Wf, const float* __restrict__ bf,
    const float* __restrict__ Wb, const float* __restrict__ bb,
    float* __restrict__ EGp)
{
    __shared__ float As[64][68];
    __shared__ float Bs[64][68];

    const int tid = threadIdx.x;
    const int tx = tid & 15, ty = tid >> 4;
    const int m0 = blockIdx.y * 64;
    const int n0 = blockIdx.x * 64;

    const float* Bsrc;
    const float* bias;
    if (n0 < 512) { Bsrc = Wf + n0 * EE; bias = bf + n0; }
    else          { Bsrc = Wb + (n0 - 512) * EE; bias = bb + (n0 - 512); }

    float acc[4][4] = {};

    for (int kc = 0; kc < 2; ++kc) {
        for (int c = tid; c < 1024; c += 256) {
            int r = c >> 4, q = c & 15;
            float4 av = *(const float4*)(emb + (size_t)(m0 + r) * EE + kc * 64 + q * 4);
            As[q * 4 + 0][r] = av.x; As[q * 4 + 1][r] = av.y;
            As[q * 4 + 2][r] = av.z; As[q * 4 + 3][r] = av.w;
            float4 bv = *(const float4*)(Bsrc + (size_t)r * EE + kc * 64 + q * 4);
            Bs[q * 4 + 0][r] = bv.x; Bs[q * 4 + 1][r] = bv.y;
            Bs[q * 4 + 2][r] = bv.z; Bs[q * 4 + 3][r] = bv.w;
        }
        __syncthreads();
        #pragma unroll 8
        for (int k = 0; k < 64; ++k) {
            float4 a4 = *(const float4*)&As[k][4 * ty];
            float4 b4 = *(const float4*)&Bs[k][4 * tx];
            float a[4] = {a4.x, a4.y, a4.z, a4.w};
            float b[4] = {b4.x, b4.y, b4.z, b4.w};
            #pragma unroll
            for (int i = 0; i < 4; ++i)
                #pragma unroll
                for (int jn = 0; jn < 4; ++jn)
                    acc[i][jn] = fmaf(a[i], b[jn], acc[i][jn]);
        }
        __syncthreads();
    }

    #pragma unroll
    for (int i = 0; i < 4; ++i) {
        int m = m0 + 4 * ty + i;                 // vocab index v
        #pragma unroll
        for (int jn = 0; jn < 4; ++jn) {
            int nn = 4 * tx + jn;
            int n = n0 + nn;                     // combined gate col
            int d = n >> 9;
            int r = n & 511;
            int slot = (r >> 7) & 1;
            int p = (r & 127) + (r >= 256 ? 128 : 0);
            float scale = ((r >> 7) == 2) ? L2E2 : L2E;   // gate g: 2*log2e
            EGp[(((size_t)m * 2 + d) * 256 + p) * 2 + slot] =
                (acc[i][jn] + bias[nn]) * scale;
        }
    }
}

// ---------------------------------------------------------------------------
// Kernel 2: fused LSTM recurrence + ragged segment max-pool.
// Base = round-22 (1156 us lstm_rec): 128 blocks (b,dir), 4 waves,
// 1 wave/SIMD; k-split (8 b128 reads/lane); DPP gate exchange; rcp
// activations; distance-2 EG prefetch; LDS-only barrier; publish-first.
//
// Round-23 (this): two serial-path cuts:
//  1. EG gather + token load moved AFTER the dot loop — their addr-calc/
//     issue (~15-20 cy) no longer delays the dots; load still has >2400 cy
//     of cover (>> 900 cy HBM miss).
//  2. log2e folded into weights + EG per gate (g gets 2*log2e) — removes
//     the v_mul before every v_exp on the serial gate path (exp2-native).
// ---------------------------------------------------------------------------

#define LSTM_STEP(T_, BUF_, XV_, TOKN_, ISSUE_)                              \
  {                                                                          \
    float2 xv_ = (XV_);          /* capture BEFORE in-place reload */        \
    float c0a = 0.f, c1a = 0.f, c2a = 0.f, c3a = 0.f;                        \
    float c0b = 0.f, c1b = 0.f, c2b = 0.f, c3b = 0.f;                        \
    const int4* hb4 = (const int4*)&hpk[BUF_][hoff];                         \
    _Pragma("unroll")                                                        \
    for (int k8 = 0; k8 < 8; k8 += 2) {                                      \
      int4 u0 = hb4[k8];                                                     \
      int4 u1 = hb4[k8 + 1];                                                 \
      h2f h0 = __builtin_bit_cast(h2f, u0.x);                                \
      h2f h1 = __builtin_bit_cast(h2f, u0.y);                                \
      h2f h2 = __builtin_bit_cast(h2f, u0.z);                                \
      h2f h3 = __builtin_bit_cast(h2f, u0.w);                                \
      h2f h4 = __builtin_bit_cast(h2f, u1.x);                                \
      h2f h5 = __builtin_bit_cast(h2f, u1.y);                                \
      h2f h6 = __builtin_bit_cast(h2f, u1.z);                                \
      h2f h7 = __builtin_bit_cast(h2f, u1.w);                                \
      c0a = dot2acc(wg[0][4 * k8 + 0], h0, c0a);                             \
      c1a = dot2acc(wg[1][4 * k8 + 0], h0, c1a);                             \
      c2a = dot2acc(wg[2][4 * k8 + 0], h0, c2a);                             \
      c3a = dot2acc(wg[3][4 * k8 + 0], h0, c3a);                             \
      c0b = dot2acc(wg[0][4 * k8 + 4], h4, c0b);                             \
      c1b = dot2acc(wg[1][4 * k8 + 4], h4, c1b);                             \
      c2b = dot2acc(wg[2][4 * k8 + 4], h4, c2b);                             \
      c3b = dot2acc(wg[3][4 * k8 + 4], h4, c3b);                             \
      c0a = dot2acc(wg[0][4 * k8 + 1], h1, c0a);                             \
      c1a = dot2acc(wg[1][4 * k8 + 1], h1, c1a);                             \
      c2a = dot2acc(wg[2][4 * k8 + 1], h1, c2a);                             \
      c3a = dot2acc(wg[3][4 * k8 + 1], h1, c3a);                             \
      c0b = dot2acc(wg[0][4 * k8 + 5], h5, c0b);                             \
      c1b = dot2acc(wg[1][4 * k8 + 5], h5, c1b);                             \
      c2b = dot2acc(wg[2][4 * k8 + 5], h5, c2b);                             \
      c3b = dot2acc(wg[3][4 * k8 + 5], h5, c3b);                             \
      c0a = dot2acc(wg[0][4 * k8 + 2], h2, c0a);                             \
      c1a = dot2acc(wg[1][4 * k8 + 2], h2, c1a);                             \
      c2a = dot2acc(wg[2][4 * k8 + 2], h2, c2a);                             \
      c3a = dot2acc(wg[3][4 * k8 + 2], h2, c3a);                             \
      c0b = dot2acc(wg[0][4 * k8 + 6], h6, c0b);                             \
      c1b = dot2acc(wg[1][4 * k8 + 6], h6, c1b);                             \
      c2b = dot2acc(wg[2][4 * k8 + 6], h6, c2b);                             \
      c3b = dot2acc(wg[3][4 * k8 + 6], h6, c3b);                             \
      c0a = dot2acc(wg[0][4 * k8 + 3], h3, c0a);                             \
      c1a = dot2acc(wg[1][4 * k8 + 3], h3, c1a);                             \
      c2a = dot2acc(wg[2][4 * k8 + 3], h3, c2a);                             \
      c3a = dot2acc(wg[3][4 * k8 + 3], h3, c3a);                             \
      c0b = dot2acc(wg[0][4 * k8 + 7], h7, c0b);                             \
      c1b = dot2acc(wg[1][4 * k8 + 7], h7, c1b);                             \
      c2b = dot2acc(wg[2][4 * k8 + 7], h7, c2b);                             \
      c3b = dot2acc(wg[3][4 * k8 + 7], h7, c3b);                             \
    }                                                                        \
    /* EG gather for T_+2 issued AFTER the dots (r23: off the dot path) */   \
    if (ISSUE_) {                                                            \
      (XV_) = egp[((size_t)(TOKN_) * 2 + dir) * 256 + p];                    \
      int i4_ = dir ? (L - 5 - (T_)) : ((T_) + 4);          /* tok T_+4 */   \
      i4_ = max(0, min(TT - 1, i4_));                                        \
      (TOKN_) = srow[i4_];                                                   \
    }                                                                        \
    float o0 = c0a + c0b;   /* partial i-preact (own k-half, scaled) */      \
    float o1 = c1a + c1b;   /* partial f-preact */                           \
    float o2 = c2a + c2b;   /* partial g-preact (scaled 2*log2e) */          \
    float o3 = c3a + c3b;   /* partial o-preact */                           \
    float x0 = xor1_swap(o0);                                                \
    float x1 = xor1_swap(o1);                                                \
    float x2 = xor1_swap(o2);                                                \
    float x3 = xor1_swap(o3);                                                \
    float g0 = (evn ? (o0 + x0) : (o2 + x2)) + xv_.x;  /* i | g preact */    \
    float g1 = (evn ? (o1 + x1) : (o3 + x3)) + xv_.y;  /* f | o preact */    \
    float s_own = sig2(g1);                            /* sf | so */         \
    float t_own = evn ? sig2(g0) : tanh2(g0);          /* si | tg */         \
    float t_x = xor1_swap(t_own);                                            \
    float s_x = xor1_swap(s_own);                                            \
    c = s_own * c + t_own * t_x;                                             \
    float hn = s_x * tanh_c(c);                                              \
    /* publish FIRST: write drains while pooling bookkeeping runs */         \
    if (evn) ((_Float16*)hpk[(BUF_) ^ 1])[u] = (_Float16)hn;                 \
    const int tt_ = dir ? (L - 1 - (T_)) : (T_);                             \
    bool bnd_ = dir ? (tt_ < nb) : (tt_ >= nb);                              \
    if (bnd_) {                                                              \
      if (evn) {                                                             \
        float v = pm;                                                        \
        if (haspad && cur_seg >= padlo) v = fmaxf(v, 0.f);                   \
        pws[(((size_t)b * 2 + dir) * SS + cur_seg) * H2 + u] = v;            \
      }                                                                      \
      pm = -INFINITY;                                                        \
      cur_seg += dir ? -1 : 1;                                               \
      nb += dir ? -wseg : wseg;                                              \
    }                                                                        \
    pm = fmaxf(pm, hn);                                                      \
    lds_barrier();                                                           \
  }

__global__ __launch_bounds__(256, 1) void lstm_rec(
    const int* __restrict__ sentence, const int* __restrict__ lens,
    const float* __restrict__ Whhf, const float* __restrict__ Whhb,
    const float* __restrict__ EGp, float* __restrict__ pws)
{
    const int bid = blockIdx.x;
    const int b = bid >> 1;
    const int dir = bid & 1;            // 0 = forward, 1 = backward
    const int tid = threadIdx.x;
    const int l = tid & 63;             // lane in wave
    const int wv = tid >> 6;            // wave 0..3
    const int u = wv * 32 + (l >> 1);   // hidden unit this lane pair covers
    const bool evn = (l & 1) == 0;      // even lane: (i,f) + cell state
    const int L = lens[b];
    const int* __restrict__ srow = sentence + (size_t)b * TT;
    const float* __restrict__ Wh = (dir == 0 ? Whhf : Whhb);

    // k-half this lane covers: even k in [0,64), odd k in [64,128)
    const int kb = evn ? 0 : 64;
    const int hoff = evn ? 0 : 32;      // int offset into hpk row (64 f16 = 32 ints)

    // --- W_hh: ALL 4 gate rows of unit u, own k-half, PRE-SCALED. ---
    // wg[g] = row (g*128 + u) * (g==2 ? 2*log2e : log2e), packed f16.
    h2f wg[4][32];
    #pragma unroll
    for (int g = 0; g < 4; ++g) {
        const float wsc = (g == 2) ? L2E2 : L2E;
        const float* src = Wh + (size_t)(g * 128 + u) * H2 + kb;
        #pragma unroll
        for (int k4 = 0; k4 < 16; ++k4) {
            float4 a = *(const float4*)(src + 4 * k4);
            wg[g][2 * k4 + 0].x = (_Float16)(a.x * wsc);
            wg[g][2 * k4 + 0].y = (_Float16)(a.y * wsc);
            wg[g][2 * k4 + 1].x = (_Float16)(a.z * wsc);
            wg[g][2 * k4 + 1].y = (_Float16)(a.w * wsc);
        }
    }

    __shared__ __align__(16) int hpk[2][64];   // double-buffered packed f16 h pairs
    if (tid < 64) hpk[0][tid] = 0;

    // per-lane EG pair column (even: (i,f) of u ; odd: (g,o) of u)
    const int p = evn ? u : (128 + u);
    const float2* __restrict__ egp = (const float2*)EGp;

    float c = 0.f;
    float pm = -INFINITY;

    const int wseg = (L + SS - 1) >> 3;
    const bool haspad = (SS * wseg > L);
    const int padlo = L / wseg;
    int cur_seg = dir ? (SS - 1) : 0;
    int nb = dir ? (SS - 1) * wseg : wseg;

    // --- prefetch pipeline: EG pairs for t=0,1 in flight; tokens for t=2,3 staged ---
    float2 e0, e1;
    int tokA, tokB;
    {
        int j0 = dir ? (L - 1) : 0;
        e0 = egp[((size_t)srow[j0] * 2 + dir) * 256 + p];
        int j1 = dir ? (L - 2) : 1;  j1 = max(0, min(TT - 1, j1));
        e1 = egp[((size_t)srow[j1] * 2 + dir) * 256 + p];
        int j2 = dir ? (L - 3) : 2;  j2 = max(0, min(TT - 1, j2));
        tokA = srow[j2];
        int j3 = dir ? (L - 4) : 3;  j3 = max(0, min(TT - 1, j3));
        tokB = srow[j3];
    }

    __syncthreads();                    // hpk[0] init visible (full drain ok here)

    int t = 0;
    for (; t + 2 <= L; t += 2) {
        LSTM_STEP(t,     0, e0, tokA, true);
        LSTM_STEP(t + 1, 1, e1, tokB, true);
    }
    if (t < L) {                        // odd-L tail (t even -> buf 0)
        LSTM_STEP(t, 0, e0, tokA, false);
    }

    if (evn) {
        float v = pm;
        if (haspad && cur_seg >= padlo) v = fmaxf(v, 0.f);
        pws[(((size_t)b * 2 + dir) * SS + cur_seg) * H2 + u] = v;
    }
}

// ---------------------------------------------------------------------------
// Kernel 3: out[b,c] = b_dense[c] + sum_k flat[b,k] * W_dense[c,k]
// ---------------------------------------------------------------------------
__global__ __launch_bounds__(256) void dense_k(
    const float* __restrict__ pws, const float* __restrict__ Wd,
    const float* __restrict__ bd, float* __restrict__ out)
{
    const int b = blockIdx.x;
    const int tid = threadIdx.x;
    float a0 = 0.f, a1 = 0.f;
    for (int k = tid; k < 2048; k += 256) {
        int h = k >> 3, s = k & 7;
        int dir = h >> 7, j = h & 127;
        float v = pws[(((size_t)b * 2 + dir) * SS + s) * H2 + j];
        a0 = fmaf(v, Wd[k], a0);
        a1 = fmaf(v, Wd[2048 + k], a1);
    }
    __shared__ float r0[256], r1[256];
    r0[tid] = a0; r1[tid] = a1;
    __syncthreads();
    for (int s = 128; s > 0; s >>= 1) {
        if (tid < s) { r0[tid] += r0[tid + s]; r1[tid] += r1[tid + s]; }
        __syncthreads();
    }
    if (tid == 0) {
        out[b * 2 + 0] = r0[0] + bd[0];
        out[b * 2 + 1] = r1[0] + bd[1];
    }
}

// ---------------------------------------------------------------------------
extern "C" void kernel_launch(void* const* d_in, const int* in_sizes, int n_in,
                              void* d_out, int out_size, void* d_ws, size_t ws_size,
                              hipStream_t stream)
{
    const int*   sentence = (const int*)d_in[0];
    const int*   lens     = (const int*)d_in[1];
    const float* emb      = (const float*)d_in[2];
    const float* Wihf     = (const float*)d_in[3];
    const float* Whhf     = (const float*)d_in[4];
    const float* bf       = (const float*)d_in[5];
    const float* Wihb     = (const float*)d_in[6];
    const float* Whhb     = (const float*)d_in[7];
    const float* bb       = (const float*)d_in[8];
    const float* Wd       = (const float*)d_in[9];
    const float* bd       = (const float*)d_in[10];
    float* out = (float*)d_out;

    float* EGp = (float*)d_ws;                    // [4096][2][256][2] fp32 = 16 MB
    float* pws = EGp + (size_t)VV * 1024;         // [64][2][8][128] fp32 = 512 KB

    eg_gemm<<<dim3(16, 64), 256, 0, stream>>>(emb, Wihf, bf, Wihb, bb, EGp);
    lstm_rec<<<128, 256, 0, stream>>>(sentence, lens, Whhf, Whhb, EGp, pws);
    dense_k<<<64, 256, 0, stream>>>(pws, Wd, bd, out);
}